// Round 4
// baseline (175.101 us; speedup 1.0000x reference)
//
#include <hip/hip_runtime.h>
#include <hip/hip_bf16.h>
#include <math.h>

// Problem constants (FunctionNPairLoss): N=8192 rows, K=128 dims, 64 classes.
#define KD 128
#define NCLS 64
#define JSPLIT 8

typedef __attribute__((ext_vector_type(8))) short short8;
typedef __attribute__((ext_vector_type(4))) float f32x4;

__device__ inline void gload_lds16(const void* g, void* l) {
    __builtin_amdgcn_global_load_lds((const __attribute__((address_space(1))) unsigned int*)g,
                                     (__attribute__((address_space(3))) unsigned int*)l,
                                     16, 0, 0);
}

// ---------------- fused cvt+prep: bf16 convert, sq = ||row||^2, label counts ----------------
// 4 rows per wave, loads issued up-front for MLP (fights the harness poison-fill HBM contention)
__global__ __launch_bounds__(256) void cvtprep_kernel(const float* __restrict__ emb,
                                                      const int* __restrict__ lab,
                                                      short* __restrict__ embb,
                                                      float* __restrict__ sq,
                                                      int* __restrict__ cnt, int N) {
    int w = (blockIdx.x * 256 + threadIdx.x) >> 6;
    int l = threadIdx.x & 63;
    int r0 = w * 4;
    if (r0 >= N) return;
    float2 v[4];
#pragma unroll
    for (int r = 0; r < 4; ++r)
        v[r] = *(const float2*)&emb[(size_t)(r0 + r) * KD + l * 2];
    float s[4];
#pragma unroll
    for (int r = 0; r < 4; ++r) {
        s[r] = v[r].x * v[r].x + v[r].y * v[r].y;
        __hip_bfloat16 h0 = __float2bfloat16(v[r].x);
        __hip_bfloat16 h1 = __float2bfloat16(v[r].y);
        unsigned int pk = ((unsigned int)*(unsigned short*)&h1 << 16) | (unsigned int)*(unsigned short*)&h0;
        *(unsigned int*)&embb[(size_t)(r0 + r) * KD + l * 2] = pk;
    }
#pragma unroll
    for (int r = 0; r < 4; ++r)
        for (int m = 32; m; m >>= 1) s[r] += __shfl_xor(s[r], m, 64);
    if (l == 0) {
#pragma unroll
        for (int r = 0; r < 4; ++r) {
            sq[r0 + r] = s[r];
            atomicAdd(&cnt[lab[r0 + r]], 1);
        }
    }
}

// ---------------- scan: 64-lane exclusive prefix over label counts ----------------
__global__ void scan_kernel(const int* __restrict__ cnt, int* __restrict__ off) {
    int l = threadIdx.x;
    int v = cnt[l];
    int s = v;
    for (int m = 1; m < 64; m <<= 1) {
        int t = __shfl_up(s, m, 64);
        if (l >= m) s += t;
    }
    off[l] = s - v;
}

// ---------------- scatter: member lists per label ----------------
__global__ void scatter_kernel(const int* __restrict__ lab, const int* __restrict__ off,
                               int* __restrict__ cur, int* __restrict__ list, int N) {
    int i = blockIdx.x * 256 + threadIdx.x;
    if (i < N) {
        int c = lab[i];
        int p = atomicAdd(&cur[c], 1);
        list[off[c] + p] = i;
    }
}

// ---------------- MFMA Zall pass (UNMASKED) ----------------
// Zall[i] = sum_{ALL j} exp(sq[i]+sq[j]-2*dot(e_i,e_j)); same-label part subtracted in pair kernel.
// 128x128 tile, 4 waves 2x2, A-frags hoisted to regs; As8 then reused as 2nd B buffer
// (double-buffered 2-phase: stage t+1 issued before compute of t, one barrier per tile).
__global__ __launch_bounds__(256, 2) void zmfma_kernel(const short* __restrict__ embb,
                                                       const float* __restrict__ sq,
                                                       float* __restrict__ Z, int N) {
    __shared__ short8 As8[128 * 16];  // 32 KB: A stage, then B double-buffer slot 1
    __shared__ short8 Bs8[128 * 16];  // 32 KB: B double-buffer slot 0

    const int tid = threadIdx.x;
    const int w = tid >> 6, l = tid & 63;
    const int wr = w >> 1, wc = w & 1;
    const int i0 = blockIdx.y * 128;
    const int jBeg = blockIdx.x * (N / JSPLIT);
    const short8* embv = (const short8*)embb;

    // stage A tile and first B tile; swizzled source: LDS[row][c] = G[row][c^(row&7)]
#pragma unroll
    for (int it = 0; it < 8; ++it) {
        int lr = w * 32 + it * 4 + (l >> 4);
        int c = (l & 15) ^ (lr & 7);
        gload_lds16(embv + (size_t)(i0 + lr) * 16 + c, &As8[w * 512 + it * 64]);
    }
#pragma unroll
    for (int it = 0; it < 8; ++it) {
        int lr = w * 32 + it * 4 + (l >> 4);
        int c = (l & 15) ^ (lr & 7);
        gload_lds16(embv + (size_t)(jBeg + lr) * 16 + c, &Bs8[w * 512 + it * 64]);
    }

    float sqi[4][4];
#pragma unroll
    for (int mi = 0; mi < 4; ++mi)
#pragma unroll
        for (int r = 0; r < 4; ++r)
            sqi[mi][r] = sq[i0 + wr * 64 + mi * 16 + (l >> 4) * 4 + r];
    float zsum[4][4];
#pragma unroll
    for (int mi = 0; mi < 4; ++mi)
#pragma unroll
        for (int r = 0; r < 4; ++r) zsum[mi][r] = 0.f;

    __syncthreads();  // A and B0 staged

    // hoist A fragments (loop-invariant over j)
    short8 af[4][4];
#pragma unroll
    for (int mi = 0; mi < 4; ++mi) {
        int row = wr * 64 + mi * 16 + (l & 15);
        int rs = row * 16, rx = row & 7;
#pragma unroll
        for (int ks = 0; ks < 4; ++ks) {
            int kc = ks * 4 + (l >> 4);
            af[mi][ks] = As8[rs + (kc ^ rx)];
        }
    }
    __syncthreads();  // all waves done reading As8 -> free for B buffering

    const int nj = N / JSPLIT / 128;
    for (int jt = 0; jt < nj; ++jt) {
        short8* rb = (jt & 1) ? As8 : Bs8;   // read tile jt from here
        short8* sb = (jt & 1) ? Bs8 : As8;   // stage tile jt+1 here
        if (jt + 1 < nj) {
            int j1 = jBeg + (jt + 1) * 128;
#pragma unroll
            for (int it = 0; it < 8; ++it) {
                int lr = w * 32 + it * 4 + (l >> 4);
                int c = (l & 15) ^ (lr & 7);
                gload_lds16(embv + (size_t)(j1 + lr) * 16 + c, &sb[w * 512 + it * 64]);
            }
        }

        f32x4 acc[4][4];
#pragma unroll
        for (int mi = 0; mi < 4; ++mi)
#pragma unroll
            for (int ni = 0; ni < 4; ++ni) acc[mi][ni] = (f32x4){0.f, 0.f, 0.f, 0.f};

#pragma unroll
        for (int ks = 0; ks < 4; ++ks) {
            short8 bf[4];
            int kc = ks * 4 + (l >> 4);
#pragma unroll
            for (int ni = 0; ni < 4; ++ni) {
                int row = wc * 64 + ni * 16 + (l & 15);
                bf[ni] = rb[row * 16 + (kc ^ (row & 7))];
            }
#pragma unroll
            for (int mi = 0; mi < 4; ++mi)
#pragma unroll
                for (int ni = 0; ni < 4; ++ni)
                    acc[mi][ni] = __builtin_amdgcn_mfma_f32_16x16x32_bf16(af[mi][ks], bf[ni], acc[mi][ni], 0, 0, 0);
        }

        // epilogue: zsum += exp(sqi + sqj - 2*dot), no mask
        int j0 = jBeg + jt * 128;
        float sqj[4];
#pragma unroll
        for (int ni = 0; ni < 4; ++ni)
            sqj[ni] = sq[j0 + wc * 64 + ni * 16 + (l & 15)];
#pragma unroll
        for (int mi = 0; mi < 4; ++mi)
#pragma unroll
            for (int ni = 0; ni < 4; ++ni)
#pragma unroll
                for (int r = 0; r < 4; ++r) {
                    float D = fmaf(-2.f, acc[mi][ni][r], sqi[mi][r] + sqj[ni]);
                    zsum[mi][r] += __expf(D);
                }
        __syncthreads();  // staged sb landed; all waves done reading rb
    }

    // reduce across the 16 lanes sharing each i, atomic into Z
#pragma unroll
    for (int mi = 0; mi < 4; ++mi)
#pragma unroll
        for (int r = 0; r < 4; ++r) {
            float v = zsum[mi][r];
            v += __shfl_xor(v, 1, 64);
            v += __shfl_xor(v, 2, 64);
            v += __shfl_xor(v, 4, 64);
            v += __shfl_xor(v, 8, 64);
            if ((l & 15) == 0)
                atomicAdd(&Z[i0 + wr * 64 + mi * 16 + (l >> 4) * 4 + r], v);
        }
}

// ---------------- pair pass v4: one block per label, fully self-contained ----------------
// Stage label rows once (<=256, 64KB). Pass 1: same-label Gram -> zsub row/col sums (LDS).
// Then Zfinal = Zall - zsub (exact cancellation: identical MFMA arithmetic as zmfma).
// Pass 2: recompute Gram -> loss sum log(1 + Zfinal[anchor]*exp(-D)) over list-position p<q.
__global__ __launch_bounds__(256, 2) void pair4_kernel(const short* __restrict__ embb,
                                                       const float* __restrict__ sq,
                                                       const float* __restrict__ Z,
                                                       const int* __restrict__ cnt,
                                                       const int* __restrict__ off,
                                                       const int* __restrict__ list,
                                                       float* __restrict__ lsum) {
    __shared__ short8 Ms8[256 * 16];   // 64 KB staged rows
    __shared__ float zsubL[256];
    __shared__ float sF[256];          // sq per list position
    __shared__ float zal[256];         // Zall per list position
    __shared__ int gid[256];           // global row id per list position
    __shared__ float red[4];

    const int c = blockIdx.x;
    const int k = cnt[c], base = off[c];
    const int kp = min(k, 256);
    const int tid = threadIdx.x;
    const int w = tid >> 6, l = tid & 63;
    const int wr = w >> 1, wc = w & 1;
    const short8* embv = (const short8*)embb;

    // metadata staging
    {
        int pos = tid;
        int g = list[base + min(pos, k - 1)];
        bool ok = pos < k;
        sF[pos] = ok ? sq[g] : 0.f;
        zal[pos] = ok ? Z[g] : 0.f;
        gid[pos] = ok ? g : 0x7fffffff;
        zsubL[pos] = 0.f;
    }
    // row staging (gathered, swizzled), skip fully-padded groups
#pragma unroll
    for (int it = 0; it < 16; ++it) {
        int grp = w * 16 + it;
        if (grp * 4 >= kp) break;  // wave-uniform
        int lr = grp * 4 + (l >> 4);
        int ch = (l & 15) ^ (lr & 7);
        int g = list[base + min(lr, k - 1)];
        gload_lds16(embv + (size_t)g * 16 + ch, &Ms8[grp * 64]);
    }
    __syncthreads();

    const int nhalf = (kp > 128) ? 2 : 1;
    float part = 0.f;

    for (int pass = 0; pass < 2; ++pass) {
        for (int qi = 0; qi < nhalf; ++qi)
            for (int qj = qi; qj < nhalf; ++qj) {
                // Gram of chunk (qi,qj): rows qi*128.., cols qj*128..
                f32x4 acc[4][4];
#pragma unroll
                for (int mi = 0; mi < 4; ++mi)
#pragma unroll
                    for (int ni = 0; ni < 4; ++ni) acc[mi][ni] = (f32x4){0.f, 0.f, 0.f, 0.f};
#pragma unroll
                for (int ks = 0; ks < 4; ++ks) {
                    short8 af[4], bf[4];
                    int kc = ks * 4 + (l >> 4);
#pragma unroll
                    for (int mi = 0; mi < 4; ++mi) {
                        int row = qi * 128 + wr * 64 + mi * 16 + (l & 15);
                        af[mi] = Ms8[row * 16 + (kc ^ (row & 7))];
                    }
#pragma unroll
                    for (int ni = 0; ni < 4; ++ni) {
                        int row = qj * 128 + wc * 64 + ni * 16 + (l & 15);
                        bf[ni] = Ms8[row * 16 + (kc ^ (row & 7))];
                    }
#pragma unroll
                    for (int mi = 0; mi < 4; ++mi)
#pragma unroll
                        for (int ni = 0; ni < 4; ++ni)
                            acc[mi][ni] = __builtin_amdgcn_mfma_f32_16x16x32_bf16(af[mi], bf[ni], acc[mi][ni], 0, 0, 0);
                }

                if (pass == 0) {
                    // zsub accumulation: e = exp(+D) masked (p<k && q<k); row sums (+col sums if off-diag)
                    float rowsum[4][4];
#pragma unroll
                    for (int mi = 0; mi < 4; ++mi)
#pragma unroll
                        for (int r = 0; r < 4; ++r) rowsum[mi][r] = 0.f;
                    float colsum[4] = {0.f, 0.f, 0.f, 0.f};
#pragma unroll
                    for (int mi = 0; mi < 4; ++mi)
#pragma unroll
                        for (int ni = 0; ni < 4; ++ni) {
                            int p = qi * 128 + wr * 64 + mi * 16 + (l >> 4) * 4;
                            int q = qj * 128 + wc * 64 + ni * 16 + (l & 15);
#pragma unroll
                            for (int r = 0; r < 4; ++r) {
                                float D = fmaf(-2.f, acc[mi][ni][r], sF[p + r] + sF[q]);
                                float e = ((p + r) < k && q < k) ? __expf(D) : 0.f;
                                rowsum[mi][r] += e;
                                colsum[ni] += e;
                            }
                        }
                    // row sums: reduce over lane bits 0..3 (covers 16 cols) then LDS atomic
#pragma unroll
                    for (int mi = 0; mi < 4; ++mi)
#pragma unroll
                        for (int r = 0; r < 4; ++r) {
                            float v = rowsum[mi][r];
                            v += __shfl_xor(v, 1, 64);
                            v += __shfl_xor(v, 2, 64);
                            v += __shfl_xor(v, 4, 64);
                            v += __shfl_xor(v, 8, 64);
                            if ((l & 15) == 0)
                                atomicAdd(&zsubL[qi * 128 + wr * 64 + mi * 16 + (l >> 4) * 4 + r], v);
                        }
                    if (qi != qj) {
                        // col sums (transpose contributions): reduce over lane bits 4..5
#pragma unroll
                        for (int ni = 0; ni < 4; ++ni) {
                            float v = colsum[ni];
                            v += __shfl_xor(v, 16, 64);
                            v += __shfl_xor(v, 32, 64);
                            if ((l >> 4) == 0)
                                atomicAdd(&zsubL[qj * 128 + wc * 64 + ni * 16 + (l & 15)], v);
                        }
                    }
                } else {
                    // loss: valid pairs p<q (list positions), anchor = min global id
#pragma unroll
                    for (int mi = 0; mi < 4; ++mi)
#pragma unroll
                        for (int ni = 0; ni < 4; ++ni) {
                            int q = qj * 128 + wc * 64 + ni * 16 + (l & 15);
#pragma unroll
                            for (int r = 0; r < 4; ++r) {
                                int p = qi * 128 + wr * 64 + mi * 16 + (l >> 4) * 4 + r;
                                bool valid = (p < q) && (q < k);
                                float D = fmaf(-2.f, acc[mi][ni][r], sF[p] + sF[q]);
                                int a = gid[p], b = gid[q];
                                float z = (a < b) ? zsubL[p] : zsubL[q];  // zsubL holds Zfinal now
                                float x = valid ? z * __expf(-D) : 0.f;
                                part += __logf(1.f + x);
                            }
                        }
                }
            }
        if (pass == 0) {
            __syncthreads();  // zsub complete
            zsubL[tid] = zal[tid] - zsubL[tid];  // Zfinal in place
            __syncthreads();
        }
    }

    for (int m = 32; m; m >>= 1) part += __shfl_xor(part, m, 64);
    if (l == 0) red[w] = part;
    __syncthreads();
    if (tid == 0) lsum[c] = red[0] + red[1] + red[2] + red[3];
}

// ---------------- finalize: per-label mean, mean over valid labels ----------------
__global__ void fin_kernel(const float* __restrict__ lsum, const int* __restrict__ cnt,
                           float* __restrict__ out) {
    int c = threadIdx.x;
    float mean = 0.f;
    int valid = 0;
    if (c < NCLS) {
        long k = cnt[c];
        long np = k * (k - 1) / 2;
        if (np > 0) { mean = lsum[c] / (float)np; valid = 1; }
    }
    float sm = mean;
    int sv = valid;
    for (int m = 32; m; m >>= 1) {
        sm += __shfl_xor(sm, m, 64);
        sv += __shfl_xor(sv, m, 64);
    }
    if (c == 0) out[0] = sm / (float)max(sv, 1);
}

extern "C" void kernel_launch(void* const* d_in, const int* in_sizes, int n_in,
                              void* d_out, int out_size, void* d_ws, size_t ws_size,
                              hipStream_t stream) {
    const float* emb = (const float*)d_in[0];
    const int* lab = (const int*)d_in[1];
    float* out = (float*)d_out;
    const int N = in_sizes[1];  // 8192

    // workspace layout (4B units); [Z | lsum | cnt | cur] contiguous for one memset
    float* ws = (float*)d_ws;
    float* Z = ws;                        // N   (Zall)
    float* lsum = ws + N;                 // 64
    int* cnt = (int*)(ws + N + NCLS);     // 64
    int* cur = cnt + NCLS;                // 64
    int* off = cur + NCLS;                // 64
    int* list = off + NCLS;               // N
    float* sq = (float*)(list + N);       // N
    short* embb = (short*)(sq + N);       // N*KD bf16 (2 MB), 16B-aligned

    hipMemsetAsync(Z, 0, (size_t)(N + 3 * NCLS) * 4, stream);
    cvtprep_kernel<<<N / 16, 256, 0, stream>>>(emb, lab, embb, sq, cnt, N);
    scan_kernel<<<1, 64, 0, stream>>>(cnt, off);
    scatter_kernel<<<(N + 255) / 256, 256, 0, stream>>>(lab, off, cur, list, N);
    dim3 zgrid(JSPLIT, N / 128);
    zmfma_kernel<<<zgrid, 256, 0, stream>>>(embb, sq, Z, N);
    pair4_kernel<<<NCLS, 256, 0, stream>>>(embb, sq, Z, cnt, off, list, lsum);
    fin_kernel<<<1, 64, 0, stream>>>(lsum, cnt, out);
}